// Round 4
// baseline (514.599 us; speedup 1.0000x reference)
//
#include <hip/hip_runtime.h>
#include <hip/hip_fp16.h>

#define NN 100000
#define NPAD 100096   // 64*1564
#define EE 3200000
#define HH 128
#define CC 40

typedef _Float16 f16x8 __attribute__((ext_vector_type(8)));
typedef float f32x4 __attribute__((ext_vector_type(4)));

// rp[i] = lower_bound(edge_dst, i) — edge_dst is sorted.
__global__ void build_rp(const int* __restrict__ dst, int* __restrict__ rp) {
    int i = blockIdx.x * blockDim.x + threadIdx.x;
    if (i > NN) return;
    int lo = 0, hi = EE;
    while (lo < hi) {
        int mid = (lo + hi) >> 1;
        if (dst[mid] < i) lo = mid + 1; else hi = mid;
    }
    rp[i] = lo;
}

// f32 -> fp16, 8 elements/thread.
__global__ __launch_bounds__(256) void f32_to_f16(const float* __restrict__ in,
                                                  __half* __restrict__ out, int n) {
    int base = (blockIdx.x * 256 + threadIdx.x) * 8;
    if (base >= n) return;
    float4 a = *(const float4*)(in + base);
    float4 b = *(const float4*)(in + base + 4);
    __half2 h[4];
    h[0] = __floats2half2_rn(a.x, a.y);
    h[1] = __floats2half2_rn(a.z, a.w);
    h[2] = __floats2half2_rn(b.x, b.y);
    h[3] = __floats2half2_rn(b.z, b.w);
    *(float4*)(out + base) = *(float4*)h;
}

// Interleave (src, w) -> int2 pairs so spmm reads one stream.
__global__ __launch_bounds__(256) void prep_edges(const int* __restrict__ src,
                                                  const float* __restrict__ w,
                                                  int4* __restrict__ ew) {
    int i = blockIdx.x * 256 + threadIdx.x;
    if (i >= EE / 4) return;
    int4 s = ((const int4*)src)[i];
    float4 f = ((const float4*)w)[i];
    int4 a, b;
    a.x = s.x; a.y = __float_as_int(f.x); a.z = s.y; a.w = __float_as_int(f.y);
    b.x = s.z; b.y = __float_as_int(f.z); b.z = s.w; b.w = __float_as_int(f.w);
    ew[2 * i] = a; ew[2 * i + 1] = b;
}

// fp16 transposed weights: W0t,W1t [128][128]; W2t [64][128] zero-padded cols>=40.
__global__ __launch_bounds__(256) void prep_weights(const float* __restrict__ W0,
                                                    const float* __restrict__ W1,
                                                    const float* __restrict__ W2,
                                                    __half* __restrict__ W0t,
                                                    __half* __restrict__ W1t,
                                                    __half* __restrict__ W2t) {
    int i = blockIdx.x * 256 + threadIdx.x;
    if (i < HH * HH) {
        int c = i >> 7, k = i & 127;
        W0t[i] = __float2half_rn(W0[k * HH + c]);
        W1t[i] = __float2half_rn(W1[k * HH + c]);
    }
    if (i < 64 * HH) {
        int c = i >> 7, k = i & 127;
        W2t[i] = __float2half_rn(c < CC ? W2[k * CC + c] : 0.f);
    }
}

// One wave per node, 4 nodes/block. 16 lanes cover a 256B row (16B/lane);
// 4 lane-groups = 4 edges per gather instruction. 16 edges/iteration.
__global__ __launch_bounds__(256) void spmm_h16(const __half* __restrict__ h,
                                                const int2* __restrict__ ew,
                                                const int* __restrict__ rp,
                                                __half* __restrict__ out) {
    int node = blockIdx.x * 4 + (threadIdx.x >> 6);
    int l = threadIdx.x & 63;
    if (node >= NN) return;
    int e0 = __builtin_amdgcn_readfirstlane(rp[node]);
    int e1 = __builtin_amdgcn_readfirstlane(rp[node + 1]);
    int g = l >> 4, r = l & 15;
    const f16x8* __restrict__ hrow = (const f16x8*)h;
    float acc[8] = {};
    int e = e0;
    if ((e & 1) && e < e1) {  // peel to make e even (int4 pair-load alignment)
        int2 pr = ew[e];
        float wk = (g == 0) ? __int_as_float(pr.y) : 0.f;
        f16x8 v = hrow[(size_t)pr.x * 16 + r];
#pragma unroll
        for (int j = 0; j < 8; ++j) acc[j] = fmaf(wk, (float)v[j], acc[j]);
        ++e;
    }
    int efull = e + ((e1 - e) & ~15);
    for (; e < efull; e += 16) {
        const int4* pp = (const int4*)(ew + e + 4 * g);
        int4 pa = pp[0];
        int4 pb = pp[1];
        f16x8 v0 = hrow[(size_t)pa.x * 16 + r];
        f16x8 v1 = hrow[(size_t)pa.z * 16 + r];
        f16x8 v2 = hrow[(size_t)pb.x * 16 + r];
        f16x8 v3 = hrow[(size_t)pb.z * 16 + r];
        float w0 = __int_as_float(pa.y), w1 = __int_as_float(pa.w);
        float w2 = __int_as_float(pb.y), w3 = __int_as_float(pb.w);
#pragma unroll
        for (int j = 0; j < 8; ++j) acc[j] = fmaf(w0, (float)v0[j], acc[j]);
#pragma unroll
        for (int j = 0; j < 8; ++j) acc[j] = fmaf(w1, (float)v1[j], acc[j]);
#pragma unroll
        for (int j = 0; j < 8; ++j) acc[j] = fmaf(w2, (float)v2[j], acc[j]);
#pragma unroll
        for (int j = 0; j < 8; ++j) acc[j] = fmaf(w3, (float)v3[j], acc[j]);
    }
    if (e < e1) {  // masked tail (<16 edges)
#pragma unroll
        for (int k = 0; k < 4; ++k) {
            int idx = e + 4 * g + k;
            bool val = idx < e1;
            int2 pr = ew[val ? idx : e0];
            float wk = val ? __int_as_float(pr.y) : 0.f;
            f16x8 v = hrow[(size_t)pr.x * 16 + r];
#pragma unroll
            for (int j = 0; j < 8; ++j) acc[j] = fmaf(wk, (float)v[j], acc[j]);
        }
    }
#pragma unroll
    for (int j = 0; j < 8; ++j) {
        acc[j] += __shfl_xor(acc[j], 16);
        acc[j] += __shfl_xor(acc[j], 32);
    }
    if (l < 16) {
        __half2 hv[4];
#pragma unroll
        for (int j = 0; j < 4; ++j) hv[j] = __floats2half2_rn(acc[2 * j], acc[2 * j + 1]);
        *(float4*)(out + (size_t)node * HH + r * 8) = *(float4*)hv;
    }
}

// spmm over padded-64 fp16 rows (128B) + tanh. 8 lanes/row -> 8 edges/gather.
__global__ __launch_bounds__(256) void spmm40_tanh(const __half* __restrict__ gpad,
                                                   const int2* __restrict__ ew,
                                                   const int* __restrict__ rp,
                                                   float* __restrict__ out) {
    int node = blockIdx.x * 4 + (threadIdx.x >> 6);
    int l = threadIdx.x & 63;
    if (node >= NN) return;
    int e0 = __builtin_amdgcn_readfirstlane(rp[node]);
    int e1 = __builtin_amdgcn_readfirstlane(rp[node + 1]);
    int g = l >> 3, r = l & 7;
    const f16x8* __restrict__ grow = (const f16x8*)gpad;
    float acc[8] = {};
    int e = e0;
    if ((e & 1) && e < e1) {
        int2 pr = ew[e];
        float wk = (g == 0) ? __int_as_float(pr.y) : 0.f;
        f16x8 v = grow[(size_t)pr.x * 8 + r];
#pragma unroll
        for (int j = 0; j < 8; ++j) acc[j] = fmaf(wk, (float)v[j], acc[j]);
        ++e;
    }
    int efull = e + ((e1 - e) & ~15);
    for (; e < efull; e += 16) {
        int4 pa = *(const int4*)(ew + e + 2 * g);
        f16x8 v0 = grow[(size_t)pa.x * 8 + r];
        f16x8 v1 = grow[(size_t)pa.z * 8 + r];
        float w0 = __int_as_float(pa.y), w1 = __int_as_float(pa.w);
#pragma unroll
        for (int j = 0; j < 8; ++j) acc[j] = fmaf(w0, (float)v0[j], acc[j]);
#pragma unroll
        for (int j = 0; j < 8; ++j) acc[j] = fmaf(w1, (float)v1[j], acc[j]);
    }
    if (e < e1) {
#pragma unroll
        for (int k = 0; k < 2; ++k) {
            int idx = e + 2 * g + k;
            bool val = idx < e1;
            int2 pr = ew[val ? idx : e0];
            float wk = val ? __int_as_float(pr.y) : 0.f;
            f16x8 v = grow[(size_t)pr.x * 8 + r];
#pragma unroll
            for (int j = 0; j < 8; ++j) acc[j] = fmaf(wk, (float)v[j], acc[j]);
        }
    }
#pragma unroll
    for (int j = 0; j < 8; ++j) {
        acc[j] += __shfl_xor(acc[j], 8);
        acc[j] += __shfl_xor(acc[j], 16);
        acc[j] += __shfl_xor(acc[j], 32);
    }
    if (l < 5) {  // 5 lanes x 8 f32 = 40 outputs
        float o[8];
#pragma unroll
        for (int j = 0; j < 8; ++j) o[j] = tanhf(acc[j]);
        *(float4*)(out + (size_t)node * CC + r * 8) = *(float4*)&o[0];
        *(float4*)(out + (size_t)node * CC + r * 8 + 4) = *(float4*)&o[4];
    }
}

// MFMA fp16 GEMM + tanh: out[r][c] = tanh(A[r][:] @ W[:][c]); Wt = W^T [128][128].
__global__ __launch_bounds__(256) void gemm_mfma_tanh(const __half* __restrict__ A,
                                                      const __half* __restrict__ Wt,
                                                      __half* __restrict__ out) {
    int wave = threadIdx.x >> 6, l = threadIdx.x & 63;
    int r0 = blockIdx.x * 64 + wave * 16;
    int lr = l & 15, lg = l >> 4;
    const _Float16* Af = (const _Float16*)A;
    const _Float16* Wf = (const _Float16*)Wt;
    int arow = r0 + lr;
    f16x8 a[4];
#pragma unroll
    for (int kb = 0; kb < 4; ++kb)
        a[kb] = *(const f16x8*)(Af + (size_t)arow * HH + kb * 32 + lg * 8);
#pragma unroll
    for (int ct = 0; ct < 8; ++ct) {
        f32x4 acc = {0.f, 0.f, 0.f, 0.f};
#pragma unroll
        for (int kb = 0; kb < 4; ++kb) {
            f16x8 b = *(const f16x8*)(Wf + (size_t)(ct * 16 + lr) * HH + kb * 32 + lg * 8);
            acc = __builtin_amdgcn_mfma_f32_16x16x32_f16(a[kb], b, acc, 0, 0, 0);
        }
#pragma unroll
        for (int r = 0; r < 4; ++r) {
            int row = r0 + lg * 4 + r;
            if (row < NN)
                out[(size_t)row * HH + ct * 16 + lr] = __float2half_rn(tanhf(acc[r]));
        }
    }
}

// g = A @ W2 (no tanh) into padded [NPAD][64]; W2t [64][128] zero-padded.
__global__ __launch_bounds__(256) void gemm40_mfma(const __half* __restrict__ A,
                                                   const __half* __restrict__ Wt,
                                                   __half* __restrict__ out) {
    int wave = threadIdx.x >> 6, l = threadIdx.x & 63;
    int r0 = blockIdx.x * 64 + wave * 16;
    int lr = l & 15, lg = l >> 4;
    const _Float16* Af = (const _Float16*)A;
    const _Float16* Wf = (const _Float16*)Wt;
    int arow = r0 + lr;
    f16x8 a[4];
#pragma unroll
    for (int kb = 0; kb < 4; ++kb)
        a[kb] = *(const f16x8*)(Af + (size_t)arow * HH + kb * 32 + lg * 8);
#pragma unroll
    for (int ct = 0; ct < 4; ++ct) {
        f32x4 acc = {0.f, 0.f, 0.f, 0.f};
#pragma unroll
        for (int kb = 0; kb < 4; ++kb) {
            f16x8 b = *(const f16x8*)(Wf + (size_t)(ct * 16 + lr) * HH + kb * 32 + lg * 8);
            acc = __builtin_amdgcn_mfma_f32_16x16x32_f16(a[kb], b, acc, 0, 0, 0);
        }
        int col = ct * 16 + lr;
#pragma unroll
        for (int r = 0; r < 4; ++r) {
            int row = r0 + lg * 4 + r;
            if (row < NN)
                out[(size_t)row * 64 + col] = __float2half_rn(acc[r]);
        }
    }
}

extern "C" void kernel_launch(void* const* d_in, const int* in_sizes, int n_in,
                              void* d_out, int out_size, void* d_ws, size_t ws_size,
                              hipStream_t stream) {
    const float* x    = (const float*)d_in[0];
    const int*   esrc = (const int*)d_in[1];
    const int*   edst = (const int*)d_in[2];
    const float* ew_f = (const float*)d_in[3];
    const float* W0   = (const float*)d_in[4];
    const float* W1   = (const float*)d_in[5];
    const float* W2   = (const float*)d_in[6];
    float* out = (float*)d_out;

    char* ws = (char*)d_ws;
    size_t off = 0;
    int* rp = (int*)(ws + off);          off += (((size_t)(NN + 1) * 4) + 511) & ~(size_t)511;
    __half* buf0 = (__half*)(ws + off);  off += (size_t)NPAD * HH * sizeof(__half); // xh, later gb
    __half* sA = (__half*)(ws + off);    off += (size_t)NPAD * HH * sizeof(__half);
    __half* hb = (__half*)(ws + off);    off += (size_t)NPAD * HH * sizeof(__half);
    int2* ew = (int2*)(ws + off);        off += (size_t)EE * sizeof(int2);
    __half* W0t = (__half*)(ws + off);   off += (size_t)HH * HH * sizeof(__half);
    __half* W1t = (__half*)(ws + off);   off += (size_t)HH * HH * sizeof(__half);
    __half* W2t = (__half*)(ws + off);   off += (size_t)64 * HH * sizeof(__half);
    __half* xh = buf0;
    __half* gb = buf0;  // alias: xh dead after first spmm

    build_rp<<<(NN + 256) / 256, 256, 0, stream>>>(edst, rp);
    f32_to_f16<<<(NN * HH) / (256 * 8), 256, 0, stream>>>(x, xh, NN * HH);
    prep_edges<<<(EE / 4 + 255) / 256, 256, 0, stream>>>(esrc, ew_f, (int4*)ew);
    prep_weights<<<64, 256, 0, stream>>>(W0, W1, W2, W0t, W1t, W2t);

    int gemm_grid = NPAD / 64;
    // layer 1
    spmm_h16<<<NN / 4, 256, 0, stream>>>(xh, ew, rp, sA);
    gemm_mfma_tanh<<<gemm_grid, 256, 0, stream>>>(sA, W0t, hb);
    // layer 2
    spmm_h16<<<NN / 4, 256, 0, stream>>>(hb, ew, rp, sA);
    gemm_mfma_tanh<<<gemm_grid, 256, 0, stream>>>(sA, W1t, hb);
    // layer 3 reordered: g = h2 @ W2 (padded 64); out = tanh(spmm(g))
    gemm40_mfma<<<gemm_grid, 256, 0, stream>>>(hb, W2t, gb);
    spmm40_tanh<<<NN / 4, 256, 0, stream>>>(gb, ew, rp, out);
}

// Round 5
// 483.156 us; speedup vs baseline: 1.0651x; 1.0651x over previous
//
#include <hip/hip_runtime.h>
#include <hip/hip_fp16.h>

#define NN 100000
#define NPAD 100096   // 64*1564
#define EE 3200000
#define HH 128
#define CC 40

typedef _Float16 f16x8 __attribute__((ext_vector_type(8)));
typedef float f32x4 __attribute__((ext_vector_type(4)));

// tanh(x) = (e^2x - 1)/(e^2x + 1); clamp avoids inf*0=NaN. ~6 VALU ops.
__device__ __forceinline__ float fast_tanh(float x) {
    float t = __expf(2.f * fminf(x, 15.f));
    return (t - 1.f) * __builtin_amdgcn_rcpf(t + 1.f);
}

// rp[i] = lower_bound(edge_dst, i) — edge_dst is sorted.
__global__ void build_rp(const int* __restrict__ dst, int* __restrict__ rp) {
    int i = blockIdx.x * blockDim.x + threadIdx.x;
    if (i > NN) return;
    int lo = 0, hi = EE;
    while (lo < hi) {
        int mid = (lo + hi) >> 1;
        if (dst[mid] < i) lo = mid + 1; else hi = mid;
    }
    rp[i] = lo;
}

// One kernel for all prep: x->fp16, edge interleave, weight transpose/convert.
__global__ __launch_bounds__(256) void prep_all(const float* __restrict__ x,
                                                const int* __restrict__ src,
                                                const float* __restrict__ w,
                                                const float* __restrict__ W0,
                                                const float* __restrict__ W1,
                                                const float* __restrict__ W2,
                                                __half* __restrict__ xh,
                                                int4* __restrict__ ew,
                                                __half* __restrict__ W0t,
                                                __half* __restrict__ W1t,
                                                __half* __restrict__ W2t) {
    int b = blockIdx.x, tid = threadIdx.x;
    if (b < 6250) {                       // f32 -> fp16 of x: 12.8M elems, 8/thread
        int base = (b * 256 + tid) * 8;
        float4 a = *(const float4*)(x + base);
        float4 c = *(const float4*)(x + base + 4);
        __half2 h[4];
        h[0] = __floats2half2_rn(a.x, a.y);
        h[1] = __floats2half2_rn(a.z, a.w);
        h[2] = __floats2half2_rn(c.x, c.y);
        h[3] = __floats2half2_rn(c.z, c.w);
        *(float4*)(xh + base) = *(float4*)h;
    } else if (b < 9375) {                // interleave (src,w) pairs: 4 edges/thread
        int i = (b - 6250) * 256 + tid;
        int4 s = ((const int4*)src)[i];
        float4 f = ((const float4*)w)[i];
        int4 pa, pb;
        pa.x = s.x; pa.y = __float_as_int(f.x); pa.z = s.y; pa.w = __float_as_int(f.y);
        pb.x = s.z; pb.y = __float_as_int(f.z); pb.z = s.w; pb.w = __float_as_int(f.w);
        ew[2 * i] = pa; ew[2 * i + 1] = pb;
    } else {                              // weights: W0t,W1t [128][128]; W2t [64][128]
        int i = (b - 9375) * 256 + tid;
        if (i < HH * HH) {
            int c = i >> 7, k = i & 127;
            W0t[i] = __float2half_rn(W0[k * HH + c]);
            W1t[i] = __float2half_rn(W1[k * HH + c]);
        }
        if (i < 64 * HH) {
            int c = i >> 7, k = i & 127;
            W2t[i] = __float2half_rn(c < CC ? W2[k * CC + c] : 0.f);
        }
    }
}

// One wave per node, 4 nodes/block. 16 lanes x 16B cover a 256B row;
// 4 lane-groups = 4 edges per gather instruction.
__global__ __launch_bounds__(256) void spmm_h16(const __half* __restrict__ h,
                                                const int2* __restrict__ ew,
                                                const int* __restrict__ rp,
                                                __half* __restrict__ out) {
    int node = blockIdx.x * 4 + (threadIdx.x >> 6);
    int l = threadIdx.x & 63;
    if (node >= NN) return;
    int e0 = __builtin_amdgcn_readfirstlane(rp[node]);
    int e1 = __builtin_amdgcn_readfirstlane(rp[node + 1]);
    int g = l >> 4, r = l & 15;
    const f16x8* __restrict__ hrow = (const f16x8*)h;
    float acc[8] = {};
    int e = e0;
    if ((e & 1) && e < e1) {  // peel to make e even (int4 pair-load alignment)
        int2 pr = ew[e];
        float wk = (g == 0) ? __int_as_float(pr.y) : 0.f;
        f16x8 v = hrow[(size_t)pr.x * 16 + r];
#pragma unroll
        for (int j = 0; j < 8; ++j) acc[j] = fmaf(wk, (float)v[j], acc[j]);
        ++e;
    }
    int efull = e + ((e1 - e) & ~15);
    for (; e < efull; e += 16) {
        const int4* pp = (const int4*)(ew + e + 4 * g);
        int4 pa = pp[0];
        int4 pb = pp[1];
        f16x8 v0 = hrow[(size_t)pa.x * 16 + r];
        f16x8 v1 = hrow[(size_t)pa.z * 16 + r];
        f16x8 v2 = hrow[(size_t)pb.x * 16 + r];
        f16x8 v3 = hrow[(size_t)pb.z * 16 + r];
        float w0 = __int_as_float(pa.y), w1 = __int_as_float(pa.w);
        float w2 = __int_as_float(pb.y), w3 = __int_as_float(pb.w);
#pragma unroll
        for (int j = 0; j < 8; ++j) acc[j] = fmaf(w0, (float)v0[j], acc[j]);
#pragma unroll
        for (int j = 0; j < 8; ++j) acc[j] = fmaf(w1, (float)v1[j], acc[j]);
#pragma unroll
        for (int j = 0; j < 8; ++j) acc[j] = fmaf(w2, (float)v2[j], acc[j]);
#pragma unroll
        for (int j = 0; j < 8; ++j) acc[j] = fmaf(w3, (float)v3[j], acc[j]);
    }
    if (e < e1) {  // masked tail (<16 edges)
#pragma unroll
        for (int k = 0; k < 4; ++k) {
            int idx = e + 4 * g + k;
            bool val = idx < e1;
            int2 pr = ew[val ? idx : e0];
            float wk = val ? __int_as_float(pr.y) : 0.f;
            f16x8 v = hrow[(size_t)pr.x * 16 + r];
#pragma unroll
            for (int j = 0; j < 8; ++j) acc[j] = fmaf(wk, (float)v[j], acc[j]);
        }
    }
#pragma unroll
    for (int j = 0; j < 8; ++j) {
        acc[j] += __shfl_xor(acc[j], 16);
        acc[j] += __shfl_xor(acc[j], 32);
    }
    if (l < 16) {
        __half2 hv[4];
#pragma unroll
        for (int j = 0; j < 4; ++j) hv[j] = __floats2half2_rn(acc[2 * j], acc[2 * j + 1]);
        *(float4*)(out + (size_t)node * HH + r * 8) = *(float4*)hv;
    }
}

// spmm over padded-64 fp16 rows (128B) + tanh. 8 lanes/row -> 8 edges/gather.
__global__ __launch_bounds__(256) void spmm40_tanh(const __half* __restrict__ gpad,
                                                   const int2* __restrict__ ew,
                                                   const int* __restrict__ rp,
                                                   float* __restrict__ out) {
    int node = blockIdx.x * 4 + (threadIdx.x >> 6);
    int l = threadIdx.x & 63;
    if (node >= NN) return;
    int e0 = __builtin_amdgcn_readfirstlane(rp[node]);
    int e1 = __builtin_amdgcn_readfirstlane(rp[node + 1]);
    int g = l >> 3, r = l & 7;
    const f16x8* __restrict__ grow = (const f16x8*)gpad;
    float acc[8] = {};
    int e = e0;
    if ((e & 1) && e < e1) {
        int2 pr = ew[e];
        float wk = (g == 0) ? __int_as_float(pr.y) : 0.f;
        f16x8 v = grow[(size_t)pr.x * 8 + r];
#pragma unroll
        for (int j = 0; j < 8; ++j) acc[j] = fmaf(wk, (float)v[j], acc[j]);
        ++e;
    }
    int efull = e + ((e1 - e) & ~15);
    for (; e < efull; e += 16) {
        int4 pa = *(const int4*)(ew + e + 2 * g);
        f16x8 v0 = grow[(size_t)pa.x * 8 + r];
        f16x8 v1 = grow[(size_t)pa.z * 8 + r];
        float w0 = __int_as_float(pa.y), w1 = __int_as_float(pa.w);
#pragma unroll
        for (int j = 0; j < 8; ++j) acc[j] = fmaf(w0, (float)v0[j], acc[j]);
#pragma unroll
        for (int j = 0; j < 8; ++j) acc[j] = fmaf(w1, (float)v1[j], acc[j]);
    }
    if (e < e1) {
#pragma unroll
        for (int k = 0; k < 2; ++k) {
            int idx = e + 2 * g + k;
            bool val = idx < e1;
            int2 pr = ew[val ? idx : e0];
            float wk = val ? __int_as_float(pr.y) : 0.f;
            f16x8 v = grow[(size_t)pr.x * 8 + r];
#pragma unroll
            for (int j = 0; j < 8; ++j) acc[j] = fmaf(wk, (float)v[j], acc[j]);
        }
    }
#pragma unroll
    for (int j = 0; j < 8; ++j) {
        acc[j] += __shfl_xor(acc[j], 8);
        acc[j] += __shfl_xor(acc[j], 16);
        acc[j] += __shfl_xor(acc[j], 32);
    }
    if (l < 5) {
        float o[8];
#pragma unroll
        for (int j = 0; j < 8; ++j) o[j] = fast_tanh(acc[j]);
        *(float4*)(out + (size_t)node * CC + r * 8) = *(float4*)&o[0];
        *(float4*)(out + (size_t)node * CC + r * 8 + 4) = *(float4*)&o[4];
    }
}

// Layer-1 GEMM: out = tanh(A @ W) fp16, epilogue coalesced via LDS.
__global__ __launch_bounds__(256) void gemm_tanh_mfma(const __half* __restrict__ A,
                                                      const __half* __restrict__ Wt,
                                                      __half* __restrict__ out) {
    __shared__ _Float16 st[4][16][136];
    int wave = threadIdx.x >> 6, l = threadIdx.x & 63;
    int r0 = blockIdx.x * 64 + wave * 16;
    int lr = l & 15, lg = l >> 4;
    const _Float16* Af = (const _Float16*)A;
    const _Float16* Wf = (const _Float16*)Wt;
    f16x8 a[4];
#pragma unroll
    for (int kb = 0; kb < 4; ++kb)
        a[kb] = *(const f16x8*)(Af + (size_t)(r0 + lr) * HH + kb * 32 + lg * 8);
#pragma unroll
    for (int ct = 0; ct < 8; ++ct) {
        f32x4 acc = {0.f, 0.f, 0.f, 0.f};
#pragma unroll
        for (int kb = 0; kb < 4; ++kb) {
            f16x8 b = *(const f16x8*)(Wf + (size_t)(ct * 16 + lr) * HH + kb * 32 + lg * 8);
            acc = __builtin_amdgcn_mfma_f32_16x16x32_f16(a[kb], b, acc, 0, 0, 0);
        }
#pragma unroll
        for (int r = 0; r < 4; ++r)
            st[wave][lg * 4 + r][ct * 16 + lr] = (_Float16)fast_tanh(acc[r]);
    }
    // coalesced stores: 4 instrs, each 4 full 256B rows (wave-private LDS, no barrier)
#pragma unroll
    for (int i = 0; i < 4; ++i) {
        int row = lg + 4 * i;
        int grow = r0 + row;
        f16x8 v = *(const f16x8*)&st[wave][row][lr * 8];
        if (grow < NN)
            *(f16x8*)((_Float16*)out + (size_t)grow * HH + lr * 8) = v;
    }
}

// Layer-2 fused: h2 = tanh(A @ W1) (LDS only), g = h2 @ W2 -> gout [NPAD][64] fp16.
__global__ __launch_bounds__(256) void gemm2_fused(const __half* __restrict__ A,
                                                   const __half* __restrict__ W1t,
                                                   const __half* __restrict__ W2t,
                                                   __half* __restrict__ gout) {
    __shared__ _Float16 st[4][16][136];
    int wave = threadIdx.x >> 6, l = threadIdx.x & 63;
    int r0 = blockIdx.x * 64 + wave * 16;
    int lr = l & 15, lg = l >> 4;
    const _Float16* Af = (const _Float16*)A;
    const _Float16* W1f = (const _Float16*)W1t;
    const _Float16* W2f = (const _Float16*)W2t;
    f16x8 a[4];
#pragma unroll
    for (int kb = 0; kb < 4; ++kb)
        a[kb] = *(const f16x8*)(Af + (size_t)(r0 + lr) * HH + kb * 32 + lg * 8);
#pragma unroll
    for (int ct = 0; ct < 8; ++ct) {
        f32x4 acc = {0.f, 0.f, 0.f, 0.f};
#pragma unroll
        for (int kb = 0; kb < 4; ++kb) {
            f16x8 b = *(const f16x8*)(W1f + (size_t)(ct * 16 + lr) * HH + kb * 32 + lg * 8);
            acc = __builtin_amdgcn_mfma_f32_16x16x32_f16(a[kb], b, acc, 0, 0, 0);
        }
#pragma unroll
        for (int r = 0; r < 4; ++r)
            st[wave][lg * 4 + r][ct * 16 + lr] = (_Float16)fast_tanh(acc[r]);
    }
    // h2 tile is wave-private in LDS; re-read as A-fragments (compiler inserts lgkmcnt)
    f16x8 a2[4];
#pragma unroll
    for (int kb = 0; kb < 4; ++kb)
        a2[kb] = *(const f16x8*)&st[wave][lr][kb * 32 + lg * 8];
#pragma unroll
    for (int ct = 0; ct < 4; ++ct) {
        f32x4 acc = {0.f, 0.f, 0.f, 0.f};
#pragma unroll
        for (int kb = 0; kb < 4; ++kb) {
            f16x8 b = *(const f16x8*)(W2f + (size_t)(ct * 16 + lr) * HH + kb * 32 + lg * 8);
            acc = __builtin_amdgcn_mfma_f32_16x16x32_f16(a2[kb], b, acc, 0, 0, 0);
        }
#pragma unroll
        for (int r = 0; r < 4; ++r)
            st[wave][lg * 4 + r][ct * 16 + lr] = (_Float16)acc[r];
    }
    // g rows are 64 halves (128B): 8 lanes/row, 2 store instrs for 16 rows
#pragma unroll
    for (int i = 0; i < 2; ++i) {
        int row = (l >> 3) + 8 * i;
        int grow = r0 + row;
        f16x8 v = *(const f16x8*)&st[wave][row][(l & 7) * 8];
        if (grow < NN)
            *(f16x8*)((_Float16*)gout + (size_t)grow * 64 + (l & 7) * 8) = v;
    }
}

extern "C" void kernel_launch(void* const* d_in, const int* in_sizes, int n_in,
                              void* d_out, int out_size, void* d_ws, size_t ws_size,
                              hipStream_t stream) {
    const float* x    = (const float*)d_in[0];
    const int*   esrc = (const int*)d_in[1];
    const int*   edst = (const int*)d_in[2];
    const float* ew_f = (const float*)d_in[3];
    const float* W0   = (const float*)d_in[4];
    const float* W1   = (const float*)d_in[5];
    const float* W2   = (const float*)d_in[6];
    float* out = (float*)d_out;

    char* ws = (char*)d_ws;
    size_t off = 0;
    int* rp = (int*)(ws + off);          off += (((size_t)(NN + 1) * 4) + 511) & ~(size_t)511;
    __half* buf0 = (__half*)(ws + off);  off += (size_t)NPAD * HH * sizeof(__half); // xh, later gb
    __half* sA = (__half*)(ws + off);    off += (size_t)NPAD * HH * sizeof(__half);
    __half* hb = (__half*)(ws + off);    off += (size_t)NPAD * HH * sizeof(__half);
    int2* ew = (int2*)(ws + off);        off += (size_t)EE * sizeof(int2);
    __half* W0t = (__half*)(ws + off);   off += (size_t)HH * HH * sizeof(__half);
    __half* W1t = (__half*)(ws + off);   off += (size_t)HH * HH * sizeof(__half);
    __half* W2t = (__half*)(ws + off);   off += (size_t)64 * HH * sizeof(__half);
    __half* xh = buf0;
    __half* gb = buf0;  // alias: xh dead after first spmm

    build_rp<<<(NN + 256) / 256, 256, 0, stream>>>(edst, rp);
    prep_all<<<9439, 256, 0, stream>>>(x, esrc, ew_f, W0, W1, W2,
                                       xh, (int4*)ew, W0t, W1t, W2t);

    int gemm_grid = NPAD / 64;
    // layer 1
    spmm_h16<<<NN / 4, 256, 0, stream>>>(xh, ew, rp, sA);
    gemm_tanh_mfma<<<gemm_grid, 256, 0, stream>>>(sA, W0t, hb);
    // layer 2 + output projection fused (h2 never hits global)
    spmm_h16<<<NN / 4, 256, 0, stream>>>(hb, ew, rp, sA);
    gemm2_fused<<<gemm_grid, 256, 0, stream>>>(sA, W1t, W2t, gb);
    // layer 3: out = tanh(spmm(g))
    spmm40_tanh<<<NN / 4, 256, 0, stream>>>(gb, ew, rp, out);
}